// Round 6
// baseline (304.971 us; speedup 1.0000x reference)
//
#include <hip/hip_runtime.h>

// Problem constants (from reference)
#define BB 8
#define LL 4096
#define DIM 1024
#define HH 16
#define MM 64
#define DH 64

// Flat sizes / output offsets (outputs concatenated, read back as f32)
constexpr long long NZ = (long long)BB * LL * DIM;   // 33554432
constexpr long long NG = (long long)BB * LL * HH;    // 524288
constexpr long long O_Z   = 0;
constexpr long long O_CRY = NZ;
constexpr long long O_NEW = NZ + NG;
constexpr long long O_CC  = NZ + 2 * NG;
constexpr long long O_FR  = NZ + 3 * NG;

// native vector type for nontemporal stores (HIP float4 is a class type,
// which __builtin_nontemporal_store rejects)
typedef float nfloat4 __attribute__((ext_vector_type(4)));

// crystallised layout: int32 {0,1}. Established empirically: R1 (uint8 read)
// failed with absmax 7.5 (branch errors); R2 with runtime detection passed,
// i.e. detection selected int32. Hardcoded; detect kernel removed.

// ---------------------------------------------------------------------------
// Phase 1: pure streaming. velocity -> counters -> flags -> enforce with OLD
// frozen values (snap overwrites `newly` segments afterwards).
//  - 3 per-head flag outputs staged in LDS, written as 512B contiguous
//    block-stores (was 4B/64B-stride partial-line writes).
//  - per-(block,wave) 32-bit `newly` bitmask -> d_ws (bit r*4 + headmod4),
//    written unconditionally every call (deterministic, no zeroing needed).
//  - big output streams use non-temporal stores (write-once data; keep L3
//    for the 388MB input working set).
// ---------------------------------------------------------------------------
#define ROWS 8

__global__ __launch_bounds__(256) void crystal_main(
    const float4* __restrict__ zc4,
    const float4* __restrict__ zp4,
    const float4* __restrict__ fr4,
    const int*    __restrict__ ccount, // [B*L*H] int32
    const int*    __restrict__ cryst,  // [B*L*H] int32 bool
    unsigned int* __restrict__ masks,  // [gridDim*4] newly bitmasks
    float* __restrict__ out)
{
    __shared__ float lds_cry[ROWS * HH];
    __shared__ float lds_new[ROWS * HH];
    __shared__ float lds_cc [ROWS * HH];

    const int t   = threadIdx.x;
    const int h   = t >> 4;
    const int sub = t & 15;

    const long long row0 = (long long)blockIdx.x * ROWS;
    long long idx = row0 * (DIM / 4) + t;
    long long g   = row0 * HH + h;

    float4 zc = zc4[idx];
    float4 zp = zp4[idx];
    float4 fr = fr4[idx];
    int    cc = ccount[g];
    int    cv = cryst[g];

    unsigned int wmask = 0u;   // newly bits for this wave: bit r*4 + (h&3)

    #pragma unroll 1
    for (int r = 0; r < ROWS; ++r) {
        // ---- prefetch next row while computing this one ----
        const long long nidx = idx + (DIM / 4);
        const long long gn   = g + HH;
        float4 zcn, zpn, frn; int ccn_ = 0, cvn = 0;
        if (r < ROWS - 1) {
            zcn = zc4[nidx]; zpn = zp4[nidx]; frn = fr4[nidx];
            ccn_ = ccount[gn]; cvn = cryst[gn];
        }

        // velocity^2: exact f32 diffs, f64 accumulate (bit-identical to R2/R3)
        double s;
        {
            double dx = (double)zc.x - (double)zp.x;
            double dy = (double)zc.y - (double)zp.y;
            double dz = (double)zc.z - (double)zp.z;
            double dw = (double)zc.w - (double)zp.w;
            s = dx * dx + dy * dy + dz * dz + dw * dw;
        }
        s += __shfl_xor(s, 1);
        s += __shfl_xor(s, 2);
        s += __shfl_xor(s, 4);
        s += __shfl_xor(s, 8);

        const bool conv = sqrt(s) < 0.01;   // velocity < TAU_CONVERGE
        const int  ccn  = conv ? cc + 1 : 0;
        const bool cry  = cv != 0;
        const bool newly   = (ccn >= 2) && !cry;
        const bool crystal = cry || newly;

        nfloat4 zout;
        zout.x = crystal ? fr.x : zc.x;
        zout.y = crystal ? fr.y : zc.y;
        zout.z = crystal ? fr.z : zc.z;
        zout.w = crystal ? fr.w : zc.w;
        nfloat4 frv = { fr.x, fr.y, fr.z, fr.w };

        __builtin_nontemporal_store(zout, reinterpret_cast<nfloat4*>(out + O_Z)  + idx);
        __builtin_nontemporal_store(frv,  reinterpret_cast<nfloat4*>(out + O_FR) + idx);

        if (sub == 0) {
            lds_cry[r * HH + h] = crystal ? 1.0f : 0.0f;
            lds_new[r * HH + h] = newly   ? 1.0f : 0.0f;
            lds_cc [r * HH + h] = (float)ccn;
        }

        // newly bitmask: ballot has bits only at lanes 0,16,32,48 of the wave
        const unsigned long long bal = __ballot(newly && sub == 0);
        const unsigned int b4 = (unsigned int)((bal        & 1ull)       |
                                               ((bal >> 16) & 1ull) << 1 |
                                               ((bal >> 32) & 1ull) << 2 |
                                               ((bal >> 48) & 1ull) << 3);
        wmask |= b4 << (4 * r);

        zc = zcn; zp = zpn; fr = frn; cc = ccn_; cv = cvn;
        idx = nidx; g = gn;
    }

    if ((t & 63) == 0)
        masks[blockIdx.x * 4 + (t >> 6)] = wmask;

    __syncthreads();
    // coalesced 512B flag writes (block's g-range is contiguous: blockIdx*128)
    if (t < ROWS * HH) {
        const long long g0 = (long long)blockIdx.x * (ROWS * HH) + t;
        out[O_CRY + g0] = lds_cry[t];
        out[O_NEW + g0] = lds_new[t];
        out[O_CC  + g0] = lds_cc [t];
    }
}

// ---------------------------------------------------------------------------
// Phase 2: codebook snap for `newly` heads (~12.5%). One 64-lane wave per
// (head h, 512-row chunk). Codebook row m lives in lane m's registers
// (16 float4 = 64 VGPR), loaded ONCE per block. Work items come from the
// compact bitmasks; z rows prefetched one item ahead. f64 distance expression
// identical to R3 -> identical argmin decisions.
// ---------------------------------------------------------------------------
#define MB_PER_CHUNK 64                    // main-blocks per snap block
#define CHUNK_ROWS  (MB_PER_CHUNK * ROWS)  // 512
#define NCHUNKS     (BB * LL / CHUNK_ROWS) // 64

__global__ __launch_bounds__(64) void crystal_snap(
    const float4* __restrict__ zc4,
    const float*  __restrict__ cb,     // [H][M][DH]
    const unsigned int* __restrict__ masks,
    float* __restrict__ out)
{
    const int lane = threadIdx.x;              // 0..63 = code index
    const int h    = blockIdx.x / NCHUNKS;     // h-major
    const int c    = blockIdx.x % NCHUNKS;
    const int w    = h >> 2;                   // wave slot within main block
    const int h2   = h & 3;                    // bit sub-position

    // my main-block's 8-row newly mask for head h
    const int mb = c * MB_PER_CHUNK + lane;
    const unsigned int word = masks[mb * 4 + w];
    unsigned int rows8 = 0u;
    #pragma unroll
    for (int r = 0; r < ROWS; ++r)
        rows8 |= ((word >> (4 * r + h2)) & 1u) << r;

    unsigned long long act = __ballot(rows8 != 0u);
    if (act == 0ull) return;

    // codebook row `lane` into registers (16 float4, coalesced 16KB/wave)
    const float* cbh = cb + (long long)h * MM * DH;
    float4 crow[16];
    {
        const float4* cp = reinterpret_cast<const float4*>(cbh + lane * DH);
        #pragma unroll
        for (int k = 0; k < 16; ++k) crow[k] = cp[k];
    }

    // uniform work-item iterator over (lane, row) bits
    int curl = 0; unsigned int curm8 = 0u;
    auto next_bl = [&]() -> long long {
        while (curm8 == 0u) {
            if (act == 0ull) return -1;
            curl = __ffsll(act) - 1; act &= act - 1;
            curm8 = __shfl(rows8, curl);
        }
        const int r = __ffs(curm8) - 1; curm8 &= curm8 - 1;
        return (long long)(c * MB_PER_CHUNK + curl) * ROWS + r;
    };

    long long bl = next_bl();
    long long seg4 = bl * (DIM / 4) + h * (DH / 4);
    float4 zv;
    if (lane < 16) zv = zc4[seg4 + lane];      // lane k holds z chunk k

    while (bl >= 0) {
        // prefetch next item's z
        const long long bln = next_bl();
        const long long seg4n = bln * (DIM / 4) + h * (DH / 4);
        float4 zvn;
        if (bln >= 0 && lane < 16) zvn = zc4[seg4n + lane];

        // distance: single f64 accumulator, same expression order as R3
        double d2 = 0.0;
        #pragma unroll
        for (int k = 0; k < 16; ++k) {
            float4 zk;
            zk.x = __shfl(zv.x, k);
            zk.y = __shfl(zv.y, k);
            zk.z = __shfl(zv.z, k);
            zk.w = __shfl(zv.w, k);
            double a  = (double)zk.x - (double)crow[k].x;
            double b  = (double)zk.y - (double)crow[k].y;
            double cq = (double)zk.z - (double)crow[k].z;
            double d  = (double)zk.w - (double)crow[k].w;
            d2 += a * a + b * b + cq * cq + d * d;
        }

        double best = d2;
        int bidx = lane;
        #pragma unroll
        for (int m2 = 1; m2 <= 32; m2 <<= 1) {
            double ob = __shfl_xor(best, m2);
            int    oi = __shfl_xor(bidx, m2);
            if (ob < best || (ob == best && oi < bidx)) { best = ob; bidx = oi; }
        }

        if (lane < 16) {
            const float4 ev = reinterpret_cast<const float4*>(cbh + bidx * DH)[lane];
            reinterpret_cast<float4*>(out + O_Z)[seg4 + lane]  = ev;
            reinterpret_cast<float4*>(out + O_FR)[seg4 + lane] = ev;
        }

        bl = bln; seg4 = seg4n; zv = zvn;
    }
}

extern "C" void kernel_launch(void* const* d_in, const int* in_sizes, int n_in,
                              void* d_out, int out_size, void* d_ws, size_t ws_size,
                              hipStream_t stream) {
    const float4* zc4 = (const float4*)d_in[0];
    const float4* zp4 = (const float4*)d_in[1];
    const float*  cb  = (const float*)d_in[2];
    const float4* fr4 = (const float4*)d_in[3];
    const int*    cc  = (const int*)d_in[4];
    const int*    cry = (const int*)d_in[5];
    float* out = (float*)d_out;
    unsigned int* masks = (unsigned int*)d_ws;   // 64KB of scratch

    hipLaunchKernelGGL(crystal_main, dim3((BB * LL) / ROWS), dim3(256), 0, stream,
                       zc4, zp4, fr4, cc, cry, masks, out);
    hipLaunchKernelGGL(crystal_snap, dim3(HH * NCHUNKS), dim3(64), 0, stream,
                       zc4, cb, masks, out);
}

// Round 7
// 231.383 us; speedup vs baseline: 1.3180x; 1.3180x over previous
//
#include <hip/hip_runtime.h>

// Problem constants (from reference)
#define BB 8
#define LL 4096
#define DIM 1024
#define HH 16
#define MM 64
#define DH 64

// Flat sizes / output offsets (outputs concatenated, read back as f32)
constexpr long long NZ = (long long)BB * LL * DIM;   // 33554432
constexpr long long NG = (long long)BB * LL * HH;    // 524288
constexpr long long O_Z   = 0;
constexpr long long O_CRY = NZ;
constexpr long long O_NEW = NZ + NG;
constexpr long long O_CC  = NZ + 2 * NG;
constexpr long long O_FR  = NZ + 3 * NG;

// native vector type for nontemporal stores (HIP float4 is a class type,
// which __builtin_nontemporal_store rejects)
typedef float nfloat4 __attribute__((ext_vector_type(4)));

// crystallised layout: int32 {0,1} (established empirically R1 vs R2).

// ---------------------------------------------------------------------------
// Phase 1: pure streaming (unchanged from R5 — measured ~110us, ~94% of its
// 652MB copy roofline). velocity -> counters -> flags -> enforce with OLD
// frozen values; snap overwrites `newly` segments afterwards.
// ---------------------------------------------------------------------------
#define ROWS 8

__global__ __launch_bounds__(256) void crystal_main(
    const float4* __restrict__ zc4,
    const float4* __restrict__ zp4,
    const float4* __restrict__ fr4,
    const int*    __restrict__ ccount, // [B*L*H] int32
    const int*    __restrict__ cryst,  // [B*L*H] int32 bool
    unsigned int* __restrict__ masks,  // [gridDim*4] newly bitmasks
    float* __restrict__ out)
{
    __shared__ float lds_cry[ROWS * HH];
    __shared__ float lds_new[ROWS * HH];
    __shared__ float lds_cc [ROWS * HH];

    const int t   = threadIdx.x;
    const int h   = t >> 4;
    const int sub = t & 15;

    const long long row0 = (long long)blockIdx.x * ROWS;
    long long idx = row0 * (DIM / 4) + t;
    long long g   = row0 * HH + h;

    float4 zc = zc4[idx];
    float4 zp = zp4[idx];
    float4 fr = fr4[idx];
    int    cc = ccount[g];
    int    cv = cryst[g];

    unsigned int wmask = 0u;   // newly bits for this wave: bit r*4 + (h&3)

    #pragma unroll 1
    for (int r = 0; r < ROWS; ++r) {
        // ---- prefetch next row while computing this one ----
        const long long nidx = idx + (DIM / 4);
        const long long gn   = g + HH;
        float4 zcn, zpn, frn; int ccn_ = 0, cvn = 0;
        if (r < ROWS - 1) {
            zcn = zc4[nidx]; zpn = zp4[nidx]; frn = fr4[nidx];
            ccn_ = ccount[gn]; cvn = cryst[gn];
        }

        // velocity^2: exact f32 diffs, f64 accumulate (bit-identical to R2-R5)
        double s;
        {
            double dx = (double)zc.x - (double)zp.x;
            double dy = (double)zc.y - (double)zp.y;
            double dz = (double)zc.z - (double)zp.z;
            double dw = (double)zc.w - (double)zp.w;
            s = dx * dx + dy * dy + dz * dz + dw * dw;
        }
        s += __shfl_xor(s, 1);
        s += __shfl_xor(s, 2);
        s += __shfl_xor(s, 4);
        s += __shfl_xor(s, 8);

        const bool conv = sqrt(s) < 0.01;   // velocity < TAU_CONVERGE
        const int  ccn  = conv ? cc + 1 : 0;
        const bool cry  = cv != 0;
        const bool newly   = (ccn >= 2) && !cry;
        const bool crystal = cry || newly;

        nfloat4 zout;
        zout.x = crystal ? fr.x : zc.x;
        zout.y = crystal ? fr.y : zc.y;
        zout.z = crystal ? fr.z : zc.z;
        zout.w = crystal ? fr.w : zc.w;
        nfloat4 frv = { fr.x, fr.y, fr.z, fr.w };

        __builtin_nontemporal_store(zout, reinterpret_cast<nfloat4*>(out + O_Z)  + idx);
        __builtin_nontemporal_store(frv,  reinterpret_cast<nfloat4*>(out + O_FR) + idx);

        if (sub == 0) {
            lds_cry[r * HH + h] = crystal ? 1.0f : 0.0f;
            lds_new[r * HH + h] = newly   ? 1.0f : 0.0f;
            lds_cc [r * HH + h] = (float)ccn;
        }

        // newly bitmask: ballot has bits only at lanes 0,16,32,48 of the wave
        const unsigned long long bal = __ballot(newly && sub == 0);
        const unsigned int b4 = (unsigned int)((bal        & 1ull)       |
                                               ((bal >> 16) & 1ull) << 1 |
                                               ((bal >> 32) & 1ull) << 2 |
                                               ((bal >> 48) & 1ull) << 3);
        wmask |= b4 << (4 * r);

        zc = zcn; zp = zpn; fr = frn; cc = ccn_; cv = cvn;
        idx = nidx; g = gn;
    }

    if ((t & 63) == 0)
        masks[blockIdx.x * 4 + (t >> 6)] = wmask;

    __syncthreads();
    // coalesced 512B flag writes (block's g-range is contiguous: blockIdx*128)
    if (t < ROWS * HH) {
        const long long g0 = (long long)blockIdx.x * (ROWS * HH) + t;
        out[O_CRY + g0] = lds_cry[t];
        out[O_NEW + g0] = lds_new[t];
        out[O_CC  + g0] = lds_cc [t];
    }
}

// ---------------------------------------------------------------------------
// Phase 2: codebook snap. R5 lesson: 1024 one-wave blocks = 1 wave/SIMD ->
// latency chains fully exposed (190us). Same structure, finer decomposition:
// MB_PER_CHUNK=4 (32 rows/wave) -> 16384 blocks -> 16 waves/SIMD queued;
// ~4 items/wave; codebook row still register-resident per block (loaded once,
// skipped entirely by the ~1.4% of blocks with no newly rows). Decision
// arithmetic (f64 accumulation order, argmin tiebreak) bit-identical to R3-R5.
// ---------------------------------------------------------------------------
#define MB_PER_CHUNK 4                     // main-blocks per snap block
#define CHUNK_ROWS  (MB_PER_CHUNK * ROWS)  // 32
#define NCHUNKS     (BB * LL / CHUNK_ROWS) // 1024

__global__ __launch_bounds__(64) void crystal_snap(
    const float4* __restrict__ zc4,
    const float*  __restrict__ cb,     // [H][M][DH]
    const unsigned int* __restrict__ masks,
    float* __restrict__ out)
{
    const int lane = threadIdx.x;              // 0..63 = code index
    const int h    = blockIdx.x / NCHUNKS;     // h-major
    const int c    = blockIdx.x % NCHUNKS;
    const int w    = h >> 2;                   // wave slot within main block
    const int h2   = h & 3;                    // bit sub-position

    // my main-block's 8-row newly mask for head h (lanes >= MB_PER_CHUNK idle)
    const int mb = c * MB_PER_CHUNK + lane;
    const unsigned int word = (lane < MB_PER_CHUNK) ? masks[mb * 4 + w] : 0u;
    unsigned int rows8 = 0u;
    #pragma unroll
    for (int r = 0; r < ROWS; ++r)
        rows8 |= ((word >> (4 * r + h2)) & 1u) << r;

    unsigned long long act = __ballot(rows8 != 0u);
    if (act == 0ull) return;

    // codebook row `lane` into registers (16 float4, 16KB/wave, L2-hot)
    const float* cbh = cb + (long long)h * MM * DH;
    float4 crow[16];
    {
        const float4* cp = reinterpret_cast<const float4*>(cbh + lane * DH);
        #pragma unroll
        for (int k = 0; k < 16; ++k) crow[k] = cp[k];
    }

    // uniform work-item iterator over (lane, row) bits
    int curl = 0; unsigned int curm8 = 0u;
    auto next_bl = [&]() -> long long {
        while (curm8 == 0u) {
            if (act == 0ull) return -1;
            curl = __ffsll(act) - 1; act &= act - 1;
            curm8 = __shfl(rows8, curl);
        }
        const int r = __ffs(curm8) - 1; curm8 &= curm8 - 1;
        return (long long)(c * MB_PER_CHUNK + curl) * ROWS + r;
    };

    long long bl = next_bl();
    long long seg4 = bl * (DIM / 4) + h * (DH / 4);
    float4 zv;
    if (lane < 16) zv = zc4[seg4 + lane];      // lane k holds z chunk k

    while (bl >= 0) {
        // prefetch next item's z
        const long long bln = next_bl();
        const long long seg4n = bln * (DIM / 4) + h * (DH / 4);
        float4 zvn;
        if (bln >= 0 && lane < 16) zvn = zc4[seg4n + lane];

        // distance: single f64 accumulator, same expression order as R3-R5
        double d2 = 0.0;
        #pragma unroll
        for (int k = 0; k < 16; ++k) {
            float4 zk;
            zk.x = __shfl(zv.x, k);
            zk.y = __shfl(zv.y, k);
            zk.z = __shfl(zv.z, k);
            zk.w = __shfl(zv.w, k);
            double a  = (double)zk.x - (double)crow[k].x;
            double b  = (double)zk.y - (double)crow[k].y;
            double cq = (double)zk.z - (double)crow[k].z;
            double d  = (double)zk.w - (double)crow[k].w;
            d2 += a * a + b * b + cq * cq + d * d;
        }

        double best = d2;
        int bidx = lane;
        #pragma unroll
        for (int m2 = 1; m2 <= 32; m2 <<= 1) {
            double ob = __shfl_xor(best, m2);
            int    oi = __shfl_xor(bidx, m2);
            if (ob < best || (ob == best && oi < bidx)) { best = ob; bidx = oi; }
        }

        if (lane < 16) {
            const float4 ev = reinterpret_cast<const float4*>(cbh + bidx * DH)[lane];
            reinterpret_cast<float4*>(out + O_Z)[seg4 + lane]  = ev;
            reinterpret_cast<float4*>(out + O_FR)[seg4 + lane] = ev;
        }

        bl = bln; seg4 = seg4n; zv = zvn;
    }
}

extern "C" void kernel_launch(void* const* d_in, const int* in_sizes, int n_in,
                              void* d_out, int out_size, void* d_ws, size_t ws_size,
                              hipStream_t stream) {
    const float4* zc4 = (const float4*)d_in[0];
    const float4* zp4 = (const float4*)d_in[1];
    const float*  cb  = (const float*)d_in[2];
    const float4* fr4 = (const float4*)d_in[3];
    const int*    cc  = (const int*)d_in[4];
    const int*    cry = (const int*)d_in[5];
    float* out = (float*)d_out;
    unsigned int* masks = (unsigned int*)d_ws;   // 64KB of scratch

    hipLaunchKernelGGL(crystal_main, dim3((BB * LL) / ROWS), dim3(256), 0, stream,
                       zc4, zp4, fr4, cc, cry, masks, out);
    hipLaunchKernelGGL(crystal_snap, dim3(HH * NCHUNKS), dim3(64), 0, stream,
                       zc4, cb, masks, out);
}